// Round 5
// baseline (264.778 us; speedup 1.0000x reference)
//
#include <hip/hip_runtime.h>

#define NC 14
#define DIM 96
#define PP (DIM*DIM*DIM)          // 884736 voxels per batch
#define VPT 8                     // voxels per thread (consecutive d, 32B-aligned)
#define BS  256
#define VPB (BS*VPT)              // 2048 voxels per block
#define BLOCKS_PER_B (PP/VPB)     // 432 blocks per batch -> 864 total

// R5: recombine the two measured-positive components:
//  - FUSION (R0 vs R4 split: saves ~24us by hiding mask work under sweep waits)
//  - DEPTH-3 4-buffer class pipeline (R1->R2: +8us at iso-structure)
// i.e. R0's fused kernel with its depth-1.5 class loop replaced by the
// fully-unrolled depth-3 pipeline at VPT=8.
__global__ __launch_bounds__(BS) void bkd_fused(
    const float* __restrict__ S, const float* __restrict__ T,
    const int* __restrict__ lab,
    double* __restrict__ gnum, int* __restrict__ gcnt)
{
    const int tid = threadIdx.x;
    const unsigned bq = blockIdx.x;
    const unsigned b  = bq / BLOCKS_PER_B;                 // 0/1, block-uniform
    const int p = (int)((bq - b * BLOCKS_PER_B) * VPB) + tid * VPT;
    const int d = p % DIM;                                 // multiple of 8
    const int t = p / DIM;
    const int w = t % DIM;
    const int h = t / DIM;

    const float* tp = T + (size_t)b * NC * PP + p;
    const float* sp = S + (size_t)b * NC * PP + p;

    float ZT[VPT], ZS[VPT], A[VPT];
#pragma unroll
    for (int i = 0; i < VPT; ++i) { ZT[i] = 0.f; ZS[i] = 0.f; A[i] = 0.f; }

    float4 Atl,Ath,Asl,Ash, Btl,Bth,Bsl,Bsh, Ctl,Cth,Csl,Csh, Dtl,Dth,Dsl,Dsh;

#define LOADC(P, c)                                                          \
    { const float* tq = tp + (size_t)(c) * PP;                               \
      const float* sq = sp + (size_t)(c) * PP;                               \
      P##tl = *(const float4*)tq; P##th = *(const float4*)(tq + 4);          \
      P##sl = *(const float4*)sq; P##sh = *(const float4*)(sq + 4); }

#define CONS(P)                                                              \
    { const float tv[VPT] = {P##tl.x,P##tl.y,P##tl.z,P##tl.w,                \
                             P##th.x,P##th.y,P##th.z,P##th.w};               \
      const float sv[VPT] = {P##sl.x,P##sl.y,P##sl.z,P##sl.w,                \
                             P##sh.x,P##sh.y,P##sh.z,P##sh.w};               \
      _Pragma("unroll")                                                      \
      for (int i = 0; i < VPT; ++i) {                                        \
          const float u = __expf(tv[i]);                                     \
          ZT[i] += u;                                                        \
          ZS[i] += __expf(sv[i]);                                            \
          A[i]   = fmaf(u, tv[i] - sv[i], A[i]); } }

    // depth-3, 4-buffer software pipeline over the 14 classes
    LOADC(A,0)  LOADC(B,1)  LOADC(C,2)
    LOADC(D,3)   CONS(A)    // c=0
    LOADC(A,4)   CONS(B)    // c=1
    LOADC(B,5)   CONS(C)    // c=2
    LOADC(C,6)   CONS(D)    // c=3
    LOADC(D,7)   CONS(A)    // c=4
    LOADC(A,8)   CONS(B)    // c=5
    LOADC(B,9)   CONS(C)    // c=6
    LOADC(C,10)  CONS(D)    // c=7
    LOADC(D,11)  CONS(A)    // c=8
    LOADC(A,12)  CONS(B)    // c=9
    LOADC(B,13)  CONS(C)    // c=10
    CONS(D)                 // c=11
    CONS(A)                 // c=12
    CONS(B)                 // c=13
#undef LOADC
#undef CONS

    float kl[VPT];
#pragma unroll
    for (int i = 0; i < VPT; ++i)
        kl[i] = A[i] / ZT[i] + __logf(ZS[i]) - __logf(ZT[i]);

    // ---- neighbor-label distinct-class masks (verified VPT=8 logic) ----
    const int lbase = (int)b * PP;
    unsigned mk[VPT];
#pragma unroll
    for (int i = 0; i < VPT; ++i) mk[i] = 0u;

#pragma unroll
    for (int dh = -1; dh <= 1; ++dh) {
        const int hh = h + dh;
        if ((unsigned)hh >= (unsigned)DIM) continue;
#pragma unroll
        for (int dw = -1; dw <= 1; ++dw) {
            const int ww = w + dw;
            if ((unsigned)ww >= (unsigned)DIM) continue;
            const int* rp = lab + lbase + (hh * DIM + ww) * DIM + d;
            const int4 v0 = *(const int4*)rp;
            const int4 v1 = *(const int4*)(rp + 4);
            unsigned lb[VPT + 2];                    // label bits at d-1 .. d+8
            lb[0] = (d > 0)         ? (1u << rp[-1])  : 0u;
            lb[1] = 1u << v0.x;  lb[2] = 1u << v0.y;
            lb[3] = 1u << v0.z;  lb[4] = 1u << v0.w;
            lb[5] = 1u << v1.x;  lb[6] = 1u << v1.y;
            lb[7] = 1u << v1.z;  lb[8] = 1u << v1.w;
            lb[9] = (d < DIM - VPT) ? (1u << rp[VPT]) : 0u;
            if (dh == 0 && dw == 0) {                // center row: exclude own voxel
#pragma unroll
                for (int i = 0; i < VPT; ++i) mk[i] |= lb[i] | lb[i + 2];
            } else {
#pragma unroll
                for (int i = 0; i < VPT; ++i) mk[i] |= lb[i] | lb[i + 1] | lb[i + 2];
            }
        }
    }

    // interior voxel with a single distinct neighbor class contributes nothing
    const bool hwi = (h >= 1 && h <= DIM - 2 && w >= 1 && w <= DIM - 2);
#pragma unroll
    for (int i = 0; i < VPT; ++i) {
        const int dd = d + i;
        const bool din = (dd > 0) && (dd < DIM - 1);
        if (hwi && din && (mk[i] & (mk[i] - 1)) == 0u) mk[i] = 0u;
    }

    // ---- per-class accumulate (registers) ----
    float lnum[NC];
    int   lcnt[NC];
#pragma unroll
    for (int k = 0; k < NC; ++k) { lnum[k] = 0.f; lcnt[k] = 0; }
#pragma unroll
    for (int i = 0; i < VPT; ++i) {
        const float kv = kl[i];
        const unsigned mm = mk[i];
#pragma unroll
        for (int k = 0; k < NC; ++k) {
            lnum[k] += (mm & (1u << k)) ? kv : 0.f;
            lcnt[k] += (mm >> k) & 1u;
        }
    }

    // ---- wave (64-lane) shuffle reduction ----
#pragma unroll
    for (int k = 0; k < NC; ++k) {
        float v = lnum[k];
        int   c = lcnt[k];
#pragma unroll
        for (int off = 32; off > 0; off >>= 1) {
            v += __shfl_down(v, off, 64);
            c += __shfl_down(c, off, 64);
        }
        lnum[k] = v; lcnt[k] = c;
    }

    __shared__ float s_num[NC];
    __shared__ int   s_cnt[NC];
    if (tid < NC) { s_num[tid] = 0.f; s_cnt[tid] = 0; }
    __syncthreads();
    if ((tid & 63) == 0) {
#pragma unroll
        for (int k = 0; k < NC; ++k) {
            atomicAdd(&s_num[k], lnum[k]);
            atomicAdd(&s_cnt[k], lcnt[k]);
        }
    }
    __syncthreads();
    if (tid < NC) {
        atomicAdd(&gnum[b * NC + tid], (double)s_num[tid]);
        atomicAdd(&gcnt[b * NC + tid], s_cnt[tid]);
    }
}

__global__ void bkd_final(const double* __restrict__ gnum,
                          const int* __restrict__ gcnt,
                          float* __restrict__ out)
{
    const int i = threadIdx.x;            // one block of 64 threads
    double term = 0.0;
    if (i < 2 * NC) {
        const int c = gcnt[i];
        if (c > 0) term = gnum[i] / ((double)NC * (double)c);
    }
#pragma unroll
    for (int off = 32; off > 0; off >>= 1)
        term += __shfl_down(term, off, 64);
    if (i == 0) out[0] = (float)term;
}

extern "C" void kernel_launch(void* const* d_in, const int* in_sizes, int n_in,
                              void* d_out, int out_size, void* d_ws, size_t ws_size,
                              hipStream_t stream) {
    const float* S  = (const float*)d_in[0];   // preds_S [2,14,96,96,96] f32
    const float* T  = (const float*)d_in[1];   // preds_T [2,14,96,96,96] f32
    const int* lab  = (const int*)d_in[2];     // gt_labels [2,1,96,96,96] int32
    float* out      = (float*)d_out;

    double* gnum = (double*)d_ws;                                   // [2*14]
    int*    gcnt = (int*)((char*)d_ws + 2 * NC * sizeof(double));   // [2*14]

    hipMemsetAsync(d_ws, 0, 2 * NC * (sizeof(double) + sizeof(int)), stream);

    bkd_fused<<<2 * BLOCKS_PER_B, BS, 0, stream>>>(S, T, lab, gnum, gcnt);
    bkd_final<<<1, 64, 0, stream>>>(gnum, gcnt, out);
}

// Round 6
// 238.960 us; speedup vs baseline: 1.1080x; 1.1080x over previous
//
#include <hip/hip_runtime.h>

#define NC 14
#define DIM 96
#define PP (DIM*DIM*DIM)          // 884736 voxels per batch
#define VPT 8                     // voxels per thread (consecutive d, 32B-aligned)
#define VPB (256*VPT)             // 2048 voxels per block
#define BLOCKS_PER_B (PP/VPB)     // 432 blocks per batch

// R6 = revert to R0, the measured-best variant (98us kernel / 238.6us harness).
// Session conclusion: 6 structural probes (VPT 4/8, depth 1.5/3, BS 256/1024,
// waves 3-54/CU, fused/split) ALL deliver 2.0-2.2 TB/s for this 28-stream
// 3.375MB-stride read-once pattern; 205MB / 2.15 TB/s = 95us floor, R0 = 98us.
// Deeper pipelining (R5) costs VGPR (40->132) and collapses occupancy; split
// (R4) forfeits ~24us of mask-under-sweep overlap. R0 is the optimum of the
// explored space and sits ~3% off the empirical pattern ceiling.
__global__ __launch_bounds__(256) void bkd_main(
    const float* __restrict__ S, const float* __restrict__ T,
    const int* __restrict__ lab,
    double* __restrict__ gnum, int* __restrict__ gcnt)
{
    const int tid = threadIdx.x;
    const unsigned bq = blockIdx.x;
    const unsigned b  = bq / BLOCKS_PER_B;                 // 0/1, block-uniform
    const int p = (int)((bq - b * BLOCKS_PER_B) * VPB) + tid * VPT;
    const int d = p % DIM;                                 // multiple of 8
    const int t = p / DIM;
    const int w = t % DIM;
    const int h = t / DIM;

    const float* tp = T + (size_t)b * NC * PP + p;
    const float* sp = S + (size_t)b * NC * PP + p;

    float ZT[VPT], ZS[VPT], A[VPT];
#pragma unroll
    for (int i = 0; i < VPT; ++i) { ZT[i] = 0.f; ZS[i] = 0.f; A[i] = 0.f; }

    // prefetch class 0
    float4 t0 = *(const float4*)(tp);
    float4 t1 = *(const float4*)(tp + 4);
    float4 s0 = *(const float4*)(sp);
    float4 s1 = *(const float4*)(sp + 4);

#define CONSUME()                                                            \
    {                                                                        \
        const float tv[VPT] = {t0.x, t0.y, t0.z, t0.w, t1.x, t1.y, t1.z, t1.w}; \
        const float sv[VPT] = {s0.x, s0.y, s0.z, s0.w, s1.x, s1.y, s1.z, s1.w}; \
        _Pragma("unroll")                                                    \
        for (int i = 0; i < VPT; ++i) {                                      \
            const float u = __expf(tv[i]);                                   \
            ZT[i] += u;                                                      \
            ZS[i] += __expf(sv[i]);                                          \
            A[i]   = fmaf(u, tv[i] - sv[i], A[i]);                           \
        }                                                                    \
    }

#pragma unroll 1
    for (int c = 0; c < NC - 1; ++c) {
        // issue next class's loads (independent of current math)
        const float* tpn = tp + PP;
        const float* spn = sp + PP;
        const float4 nt0 = *(const float4*)(tpn);
        const float4 nt1 = *(const float4*)(tpn + 4);
        const float4 ns0 = *(const float4*)(spn);
        const float4 ns1 = *(const float4*)(spn + 4);
        CONSUME();
        tp = tpn; sp = spn;
        t0 = nt0; t1 = nt1; s0 = ns0; s1 = ns1;
    }
    CONSUME();    // class NC-1 (peeled)
#undef CONSUME

    float kl[VPT];
#pragma unroll
    for (int i = 0; i < VPT; ++i)
        kl[i] = A[i] / ZT[i] + __logf(ZS[i]) - __logf(ZT[i]);

    // ---- neighbor-label distinct-class masks (verified VPT=8 logic) ----
    const int lbase = (int)b * PP;
    unsigned mk[VPT];
#pragma unroll
    for (int i = 0; i < VPT; ++i) mk[i] = 0u;

#pragma unroll
    for (int dh = -1; dh <= 1; ++dh) {
        const int hh = h + dh;
        if ((unsigned)hh >= (unsigned)DIM) continue;
#pragma unroll
        for (int dw = -1; dw <= 1; ++dw) {
            const int ww = w + dw;
            if ((unsigned)ww >= (unsigned)DIM) continue;
            const int* rp = lab + lbase + (hh * DIM + ww) * DIM + d;
            const int4 v0 = *(const int4*)rp;
            const int4 v1 = *(const int4*)(rp + 4);
            unsigned lb[VPT + 2];                    // label bits at d-1 .. d+8
            lb[0] = (d > 0)         ? (1u << rp[-1])  : 0u;
            lb[1] = 1u << v0.x;  lb[2] = 1u << v0.y;
            lb[3] = 1u << v0.z;  lb[4] = 1u << v0.w;
            lb[5] = 1u << v1.x;  lb[6] = 1u << v1.y;
            lb[7] = 1u << v1.z;  lb[8] = 1u << v1.w;
            lb[9] = (d < DIM - VPT) ? (1u << rp[VPT]) : 0u;
            if (dh == 0 && dw == 0) {                // center row: exclude own voxel
#pragma unroll
                for (int i = 0; i < VPT; ++i) mk[i] |= lb[i] | lb[i + 2];
            } else {
#pragma unroll
                for (int i = 0; i < VPT; ++i) mk[i] |= lb[i] | lb[i + 1] | lb[i + 2];
            }
        }
    }

    // interior voxel with a single distinct neighbor class contributes nothing
    const bool hwi = (h >= 1 && h <= DIM - 2 && w >= 1 && w <= DIM - 2);
#pragma unroll
    for (int i = 0; i < VPT; ++i) {
        const int dd = d + i;
        const bool din = (dd > 0) && (dd < DIM - 1);
        if (hwi && din && (mk[i] & (mk[i] - 1)) == 0u) mk[i] = 0u;
    }

    // ---- per-class accumulate (registers) ----
    float lnum[NC];
    int   lcnt[NC];
#pragma unroll
    for (int k = 0; k < NC; ++k) { lnum[k] = 0.f; lcnt[k] = 0; }
#pragma unroll
    for (int i = 0; i < VPT; ++i) {
        const float kv = kl[i];
        const unsigned mm = mk[i];
#pragma unroll
        for (int k = 0; k < NC; ++k) {
            lnum[k] += (mm & (1u << k)) ? kv : 0.f;
            lcnt[k] += (mm >> k) & 1u;
        }
    }

    // ---- wave (64-lane) shuffle reduction ----
#pragma unroll
    for (int k = 0; k < NC; ++k) {
        float v = lnum[k];
        int   c = lcnt[k];
#pragma unroll
        for (int off = 32; off > 0; off >>= 1) {
            v += __shfl_down(v, off, 64);
            c += __shfl_down(c, off, 64);
        }
        lnum[k] = v; lcnt[k] = c;
    }

    __shared__ float s_num[NC];
    __shared__ int   s_cnt[NC];
    if (tid < NC) { s_num[tid] = 0.f; s_cnt[tid] = 0; }
    __syncthreads();
    if ((tid & 63) == 0) {
#pragma unroll
        for (int k = 0; k < NC; ++k) {
            atomicAdd(&s_num[k], lnum[k]);
            atomicAdd(&s_cnt[k], lcnt[k]);
        }
    }
    __syncthreads();
    if (tid < NC) {
        atomicAdd(&gnum[b * NC + tid], (double)s_num[tid]);
        atomicAdd(&gcnt[b * NC + tid], s_cnt[tid]);
    }
}

__global__ void bkd_final(const double* __restrict__ gnum,
                          const int* __restrict__ gcnt,
                          float* __restrict__ out)
{
    const int i = threadIdx.x;            // one block of 64 threads
    double term = 0.0;
    if (i < 2 * NC) {
        const int c = gcnt[i];
        if (c > 0) term = gnum[i] / ((double)NC * (double)c);
    }
#pragma unroll
    for (int off = 32; off > 0; off >>= 1)
        term += __shfl_down(term, off, 64);
    if (i == 0) out[0] = (float)term;
}

extern "C" void kernel_launch(void* const* d_in, const int* in_sizes, int n_in,
                              void* d_out, int out_size, void* d_ws, size_t ws_size,
                              hipStream_t stream) {
    const float* S  = (const float*)d_in[0];   // preds_S [2,14,96,96,96] f32
    const float* T  = (const float*)d_in[1];   // preds_T [2,14,96,96,96] f32
    const int* lab  = (const int*)d_in[2];     // gt_labels [2,1,96,96,96] int32
    float* out      = (float*)d_out;

    double* gnum = (double*)d_ws;                                   // [2*14]
    int*    gcnt = (int*)((char*)d_ws + 2 * NC * sizeof(double));   // [2*14]

    hipMemsetAsync(d_ws, 0, 2 * NC * (sizeof(double) + sizeof(int)), stream);

    bkd_main<<<2 * BLOCKS_PER_B, 256, 0, stream>>>(S, T, lab, gnum, gcnt);
    bkd_final<<<1, 64, 0, stream>>>(gnum, gcnt, out);
}